// Round 3
// baseline (102.101 us; speedup 1.0000x reference)
//
#include <hip/hip_runtime.h>
#include <math.h>

#define B_ 16
#define N_ 1024
#define K_ 64
#define C_ 128
#define INV_T 14.285714285714286f  // 1/0.07
#define NBLK_MAIN 2048             // 8 rows per block (4 waves x 2 rows)

__device__ __forceinline__ float waveReduceSum(float v) {
#pragma unroll
    for (int off = 32; off > 0; off >>= 1)
        v += __shfl_xor(v, off, 64);
    return v;
}

__device__ __forceinline__ float waveReduceMax(float v) {
#pragma unroll
    for (int off = 32; off > 0; off >>= 1)
        v = fmaxf(v, __shfl_xor(v, off, 64));
    return v;
}

// Kernel 1: inverse L2 norm of each k row (16384 rows; wave per row, 4 rows/wave).
// 64KB table; per-batch slice is 4KB -> L1-resident during the gather kernel.
__global__ __launch_bounds__(256) void knorm_kernel(const float* __restrict__ k,
                                                    float* __restrict__ inv_k) {
    const int lane = threadIdx.x & 63;
    const int wid  = threadIdx.x >> 6;
    const int base = blockIdx.x * 16 + wid * 4;
#pragma unroll
    for (int r = 0; r < 4; ++r) {
        const int row = base + r;
        const float2 kv = *(const float2*)(k + (size_t)row * C_ + 2 * lane);
        float ss = waveReduceSum(kv.x * kv.x + kv.y * kv.y);
        if (lane == 0) inv_k[row] = 1.0f / fmaxf(sqrtf(ss), 1e-12f);
    }
}

// Kernel 2: one wave per q-row, 2 rows per wave (2048 blocks -> full occupancy).
// 8 lanes cooperatively read one k-row (each load instruction = 8 full 128B
// lines, touched exactly once). 9 gather passes: passes 0-7 are the 64
// negatives; pass 8 uses group 0 for the positive row and group 1 for the q
// row itself (giving q*q), so there is NO wave-wide pos/norm reduction --
// only the 3-level intra-group xor (DPP-fast) plus two readlane broadcasts.
// k-norms come from the precomputed inv_k table (L1-hot, 4KB/batch).
// No __syncthreads in the row loop: q_lds[wid] is private to wave wid.
__global__ __launch_bounds__(256, 4) void infonce_kernel(
    const float* __restrict__ q, const float* __restrict__ k,
    const int* __restrict__ pos_idx, const int* __restrict__ neg_idx,
    const float* __restrict__ inv_k, float* __restrict__ partials) {
    __shared__ float q_lds[4][C_];
    __shared__ float wave_tot[4], wave_cnt[4];

    const int lane = threadIdx.x & 63;
    const int wid  = threadIdx.x >> 6;
    const int g    = lane >> 3;   // group 0..7
    const int s    = lane & 7;    // sub-lane within group

    const int batch = blockIdx.x & 15;   // XCD-affine batch mapping
    const int chunk = blockIdx.x >> 4;   // 0..127
    const int rbase = chunk * 8 + wid * 2;

    const float* kb    = k + (size_t)batch * (N_ * C_);
    const float* invkb = inv_k + batch * N_;

    float tot = 0.0f, cnt = 0.0f;

#pragma unroll
    for (int r = 0; r < 2; ++r) {
        const int n   = rbase + r;
        const int row = batch * N_ + n;
        const float* qrow = q + (size_t)row * C_;

        // Stage q row into this wave's private LDS slot (coalesced).
        const float2 qv = *(const float2*)(qrow + 2 * lane);
        *(float2*)(&q_lds[wid][2 * lane]) = qv;

        const int  pidx = pos_idx[row];         // wave-uniform scalar load
        const bool pval = pidx >= 0;
        const int  p0   = pval ? pidx : 0;

        const int my_nidx = neg_idx[(size_t)row * K_ + lane];  // coalesced

        // Broadcast all 8 group indices up front (independent, pipelined).
        int nidx[8];
#pragma unroll
        for (int p = 0; p < 8; ++p) nidx[p] = __shfl(my_nidx, p * 8 + g, 64);

        // This lane's 16 q elements (LDS broadcast; same-wave RAW, no barrier).
        float4 q4[4];
#pragma unroll
        for (int i = 0; i < 4; ++i)
            q4[i] = *(const float4*)(&q_lds[wid][i * 32 + s * 4]);

        // 9 gather passes.
        float d[9];
#pragma unroll
        for (int p = 0; p < 9; ++p) {
            const float* kr;
            if (p < 8) kr = kb + (size_t)(nidx[p] >= 0 ? nidx[p] : 0) * C_;
            else       kr = (g == 0) ? (kb + (size_t)p0 * C_) : qrow;
            float dot = 0.0f;
#pragma unroll
            for (int i = 0; i < 4; ++i) {
                const float4 kv = *(const float4*)(kr + i * 32 + s * 4);
                dot = fmaf(kv.x, q4[i].x, dot);
                dot = fmaf(kv.y, q4[i].y, dot);
                dot = fmaf(kv.z, q4[i].z, dot);
                dot = fmaf(kv.w, q4[i].w, dot);
            }
            dot += __shfl_xor(dot, 1, 64);   // intra-row-16: DPP-fast
            dot += __shfl_xor(dot, 2, 64);
            dot += __shfl_xor(dot, 4, 64);
            d[p] = dot;
        }

        const float pos_dot = __int_as_float(__builtin_amdgcn_readlane(__float_as_int(d[8]), 0));
        const float qss     = __int_as_float(__builtin_amdgcn_readlane(__float_as_int(d[8]), 8));
        const float scale   = (1.0f / fmaxf(sqrtf(qss), 1e-12f)) * INV_T;
        const float pos_sim = pos_dot * scale * invkb[p0];

        float simv[8];
#pragma unroll
        for (int p = 0; p < 8; ++p) {
            const bool nv = nidx[p] >= 0;
            const float ik = invkb[nv ? nidx[p] : 0];   // L1-hot table
            simv[p] = nv ? d[p] * scale * ik : -INFINITY;
        }

        // logsumexp over [pos, 64 negs]; each sim duplicated across its
        // 8-lane group -> only s==0 lanes contribute to the sum.
        float m = pos_sim;
#pragma unroll
        for (int p = 0; p < 8; ++p) m = fmaxf(m, simv[p]);
        m = waveReduceMax(m);
        float ssum = 0.0f;
        if (s == 0) {
#pragma unroll
            for (int p = 0; p < 8; ++p) ssum += __expf(simv[p] - m);
        }
        ssum = waveReduceSum(ssum) + __expf(pos_sim - m);
        const float per_patch = m + __logf(ssum) - pos_sim;

        if (pval) { tot += per_patch; cnt += 1.0f; }
    }

    if (lane == 0) { wave_tot[wid] = tot; wave_cnt[wid] = cnt; }
    __syncthreads();
    if (threadIdx.x == 0) {
        partials[2 * blockIdx.x]     = wave_tot[0] + wave_tot[1] + wave_tot[2] + wave_tot[3];
        partials[2 * blockIdx.x + 1] = wave_cnt[0] + wave_cnt[1] + wave_cnt[2] + wave_cnt[3];
    }
}

// Kernel 3: reduce block partials, emit total / count.
__global__ __launch_bounds__(256) void finalize_kernel(const float* __restrict__ partials,
                                                       float* __restrict__ out, int nblocks) {
    __shared__ float st[256], sc[256];
    float t = 0.0f, c = 0.0f;
    for (int i = threadIdx.x; i < nblocks; i += 256) {
        t += partials[2 * i];
        c += partials[2 * i + 1];
    }
    st[threadIdx.x] = t;
    sc[threadIdx.x] = c;
    __syncthreads();
    for (int off = 128; off > 0; off >>= 1) {
        if (threadIdx.x < off) {
            st[threadIdx.x] += st[threadIdx.x + off];
            sc[threadIdx.x] += sc[threadIdx.x + off];
        }
        __syncthreads();
    }
    if (threadIdx.x == 0) {
        const float cntv = sc[0];
        out[0] = (cntv > 0.0f) ? st[0] / fmaxf(cntv, 1.0f) : 0.0f;
    }
}

extern "C" void kernel_launch(void* const* d_in, const int* in_sizes, int n_in,
                              void* d_out, int out_size, void* d_ws, size_t ws_size,
                              hipStream_t stream) {
    const float* q   = (const float*)d_in[0];
    const float* k   = (const float*)d_in[1];
    const int*   pos = (const int*)d_in[2];
    const int*   neg = (const int*)d_in[3];
    float* out = (float*)d_out;
    float* ws  = (float*)d_ws;

    float* partials = ws;            // 2 * NBLK_MAIN floats
    float* inv_k    = ws + 2 * NBLK_MAIN;  // B*N = 16384 floats

    knorm_kernel<<<1024, 256, 0, stream>>>(k, inv_k);
    infonce_kernel<<<NBLK_MAIN, 256, 0, stream>>>(q, k, pos, neg, inv_k, partials);
    finalize_kernel<<<1, 256, 0, stream>>>(partials, out, NBLK_MAIN);
}

// Round 4
// 90.121 us; speedup vs baseline: 1.1329x; 1.1329x over previous
//
#include <hip/hip_runtime.h>
#include <math.h>

#define B_ 16
#define N_ 1024
#define K_ 64
#define C_ 128
#define INV_T 14.285714285714286f  // 1/0.07
#define NBLK_MAIN 2048             // 8 rows per block (4 waves x 2 rows)

__device__ __forceinline__ float waveReduceSum(float v) {
#pragma unroll
    for (int off = 32; off > 0; off >>= 1)
        v += __shfl_xor(v, off, 64);
    return v;
}

__device__ __forceinline__ float waveReduceMax(float v) {
#pragma unroll
    for (int off = 32; off > 0; off >>= 1)
        v = fmaxf(v, __shfl_xor(v, off, 64));
    return v;
}

// fp32 -> bf16 round-to-nearest-even (inputs are finite normals; no NaN path).
__device__ __forceinline__ unsigned short f2bf(float x) {
    unsigned u = __float_as_uint(x);
    return (unsigned short)((u + 0x7fffu + ((u >> 16) & 1u)) >> 16);
}
// bf16 pair unpack from a packed u32 (low halfword = lower-addressed element).
__device__ __forceinline__ float bflo(unsigned u) { return __uint_as_float(u << 16); }
__device__ __forceinline__ float bfhi(unsigned u) { return __uint_as_float(u & 0xffff0000u); }

// Kernel 1: L2-normalize q and k rows into bf16 tables (4 MB each).
// 32768 rows; wave per row, 4 rows per wave -> 2048 blocks.
__global__ __launch_bounds__(256) void normalize_kernel(
    const float* __restrict__ q, const float* __restrict__ k,
    unsigned short* __restrict__ qn, unsigned short* __restrict__ kn) {
    const int lane = threadIdx.x & 63;
    const int wid  = threadIdx.x >> 6;
    const int base = blockIdx.x * 16 + wid * 4;
#pragma unroll
    for (int r = 0; r < 4; ++r) {
        const int row = base + r;                     // 0..32767
        const bool is_q = row < (B_ * N_);
        const int  rr   = is_q ? row : row - B_ * N_;
        const float* src = (is_q ? q : k) + (size_t)rr * C_;
        unsigned short* dst = (is_q ? qn : kn) + (size_t)rr * C_;
        const float2 v = *(const float2*)(src + 2 * lane);
        const float ss = waveReduceSum(v.x * v.x + v.y * v.y);
        const float inv = 1.0f / fmaxf(sqrtf(ss), 1e-12f);
        ushort2 o; o.x = f2bf(v.x * inv); o.y = f2bf(v.y * inv);
        *(ushort2*)(dst + 2 * lane) = o;              // 4 B/lane, coalesced
    }
}

// Kernel 2: one wave per q-row, 2 rows per wave. bf16 gather: 8 lanes per
// k-row (256 B = 2 x 128B lines per row; each load instruction covers 8 full
// lines touched exactly once). 9 passes: 0-7 = the 64 negatives (one row per
// 8-lane group), pass 8 = positive row read by ALL lanes (same-line requests
// coalesce -> still 2 line-fetches). Rows are pre-normalized so sims need no
// norm lookups. kn is 4 MB total / 512 KB per hot XCD slice -> L2-resident.
__global__ __launch_bounds__(256, 4) void infonce_kernel(
    const unsigned short* __restrict__ qn, const unsigned short* __restrict__ kn,
    const int* __restrict__ pos_idx, const int* __restrict__ neg_idx,
    float* __restrict__ partials) {
    __shared__ float wave_tot[4], wave_cnt[4];

    const int lane = threadIdx.x & 63;
    const int wid  = threadIdx.x >> 6;
    const int g    = lane >> 3;   // group 0..7
    const int s    = lane & 7;    // sub-lane within group

    const int batch = blockIdx.x & 15;   // XCD-affine batch mapping
    const int chunk = blockIdx.x >> 4;
    const int rbase = chunk * 8 + wid * 2;

    const unsigned short* kb = kn + (size_t)batch * (N_ * C_);

    float tot = 0.0f, cnt = 0.0f;

#pragma unroll
    for (int r = 0; r < 2; ++r) {
        const int n   = rbase + r;
        const int row = batch * N_ + n;

        // This lane's 16 q elements: [i*64 + s*8 .. +7], i=0..1 (global bcast).
        const unsigned short* qrow = qn + (size_t)row * C_;
        float qf[16];
#pragma unroll
        for (int i = 0; i < 2; ++i) {
            const uint4 qu = *(const uint4*)(qrow + i * 64 + s * 8);
            qf[i*8+0] = bflo(qu.x); qf[i*8+1] = bfhi(qu.x);
            qf[i*8+2] = bflo(qu.y); qf[i*8+3] = bfhi(qu.y);
            qf[i*8+4] = bflo(qu.z); qf[i*8+5] = bfhi(qu.z);
            qf[i*8+6] = bflo(qu.w); qf[i*8+7] = bfhi(qu.w);
        }

        const int  pidx = pos_idx[row];     // wave-uniform
        const bool pval = pidx >= 0;
        const int  p0   = pval ? pidx : 0;

        const int my_nidx = neg_idx[(size_t)row * K_ + lane];  // coalesced
        int nidx[8];
#pragma unroll
        for (int p = 0; p < 8; ++p) nidx[p] = __shfl(my_nidx, p * 8 + g, 64);

        float d[9];
#pragma unroll
        for (int p = 0; p < 9; ++p) {
            const unsigned short* kr =
                (p < 8) ? kb + (size_t)(nidx[p] >= 0 ? nidx[p] : 0) * C_
                        : kb + (size_t)p0 * C_;
            float dot = 0.0f;
#pragma unroll
            for (int i = 0; i < 2; ++i) {
                const uint4 ku = *(const uint4*)(kr + i * 64 + s * 8);
                dot = fmaf(bflo(ku.x), qf[i*8+0], dot);
                dot = fmaf(bfhi(ku.x), qf[i*8+1], dot);
                dot = fmaf(bflo(ku.y), qf[i*8+2], dot);
                dot = fmaf(bfhi(ku.y), qf[i*8+3], dot);
                dot = fmaf(bflo(ku.z), qf[i*8+4], dot);
                dot = fmaf(bfhi(ku.z), qf[i*8+5], dot);
                dot = fmaf(bflo(ku.w), qf[i*8+6], dot);
                dot = fmaf(bfhi(ku.w), qf[i*8+7], dot);
            }
            dot += __shfl_xor(dot, 1, 64);   // intra-group-8: DPP-fast
            dot += __shfl_xor(dot, 2, 64);
            dot += __shfl_xor(dot, 4, 64);
            d[p] = dot;
        }

        // Pass 8 was read by all lanes identically -> d[8] uniform already.
        const float pos_sim = d[8] * INV_T;

        float simv[8];
#pragma unroll
        for (int p = 0; p < 8; ++p)
            simv[p] = (nidx[p] >= 0) ? d[p] * INV_T : -INFINITY;

        // logsumexp over [pos, 64 negs]; sims duplicated across each group's
        // 8 lanes -> only s==0 lanes contribute to the sum.
        float m = pos_sim;
#pragma unroll
        for (int p = 0; p < 8; ++p) m = fmaxf(m, simv[p]);
        m = waveReduceMax(m);
        float ssum = 0.0f;
        if (s == 0) {
#pragma unroll
            for (int p = 0; p < 8; ++p) ssum += __expf(simv[p] - m);
        }
        ssum = waveReduceSum(ssum) + __expf(pos_sim - m);
        const float per_patch = m + __logf(ssum) - pos_sim;

        if (pval) { tot += per_patch; cnt += 1.0f; }
    }

    if (lane == 0) { wave_tot[wid] = tot; wave_cnt[wid] = cnt; }
    __syncthreads();
    if (threadIdx.x == 0) {
        partials[2 * blockIdx.x]     = wave_tot[0] + wave_tot[1] + wave_tot[2] + wave_tot[3];
        partials[2 * blockIdx.x + 1] = wave_cnt[0] + wave_cnt[1] + wave_cnt[2] + wave_cnt[3];
    }
}

// Kernel 3: reduce block partials, emit total / count.
__global__ __launch_bounds__(256) void finalize_kernel(const float* __restrict__ partials,
                                                       float* __restrict__ out, int nblocks) {
    __shared__ float st[256], sc[256];
    float t = 0.0f, c = 0.0f;
    for (int i = threadIdx.x; i < nblocks; i += 256) {
        t += partials[2 * i];
        c += partials[2 * i + 1];
    }
    st[threadIdx.x] = t;
    sc[threadIdx.x] = c;
    __syncthreads();
    for (int off = 128; off > 0; off >>= 1) {
        if (threadIdx.x < off) {
            st[threadIdx.x] += st[threadIdx.x + off];
            sc[threadIdx.x] += sc[threadIdx.x + off];
        }
        __syncthreads();
    }
    if (threadIdx.x == 0) {
        const float cntv = sc[0];
        out[0] = (cntv > 0.0f) ? st[0] / fmaxf(cntv, 1.0f) : 0.0f;
    }
}

extern "C" void kernel_launch(void* const* d_in, const int* in_sizes, int n_in,
                              void* d_out, int out_size, void* d_ws, size_t ws_size,
                              hipStream_t stream) {
    const float* q   = (const float*)d_in[0];
    const float* k   = (const float*)d_in[1];
    const int*   pos = (const int*)d_in[2];
    const int*   neg = (const int*)d_in[3];
    float* out = (float*)d_out;

    float* wsf = (float*)d_ws;
    float* partials = wsf;                                   // 4096 floats
    unsigned short* qn = (unsigned short*)(wsf + 8192);      // 4 MB
    unsigned short* kn = qn + (size_t)B_ * N_ * C_;          // 4 MB

    normalize_kernel<<<2048, 256, 0, stream>>>(q, k, qn, kn);
    infonce_kernel<<<NBLK_MAIN, 256, 0, stream>>>(qn, kn, pos, neg, partials);
    finalize_kernel<<<1, 256, 0, stream>>>(partials, out, NBLK_MAIN);
}

// Round 5
// 87.815 us; speedup vs baseline: 1.1627x; 1.0263x over previous
//
#include <hip/hip_runtime.h>
#include <math.h>

#define B_ 16
#define N_ 1024
#define K_ 64
#define C_ 128
#define INV_T 14.285714285714286f  // 1/0.07
#define NBLK_MAIN 2048             // 8 rows per block (4 waves x 2 rows)

using f32x2 = __attribute__((ext_vector_type(2))) float;

__device__ __forceinline__ float waveReduceSum(float v) {
#pragma unroll
    for (int off = 32; off > 0; off >>= 1)
        v += __shfl_xor(v, off, 64);
    return v;
}

__device__ __forceinline__ float waveReduceMax(float v) {
#pragma unroll
    for (int off = 32; off > 0; off >>= 1)
        v = fmaxf(v, __shfl_xor(v, off, 64));
    return v;
}

// fp32 -> bf16 round-to-nearest-even (finite normals only).
__device__ __forceinline__ unsigned short f2bf(float x) {
    unsigned u = __float_as_uint(x);
    return (unsigned short)((u + 0x7fffu + ((u >> 16) & 1u)) >> 16);
}
__device__ __forceinline__ float bflo(unsigned u) { return __uint_as_float(u << 16); }
__device__ __forceinline__ float bfhi(unsigned u) { return __uint_as_float(u & 0xffff0000u); }

// Kernel 1: L2-normalize. q rows -> bf16 qn (4 MB); k rows -> fp8 e4m3 kn
// (2 MB; HW v_cvt_pk_fp8_f32, OCP on gfx950). Wave per row, 4 rows/wave.
__global__ __launch_bounds__(256) void normalize_kernel(
    const float* __restrict__ q, const float* __restrict__ k,
    unsigned short* __restrict__ qn, unsigned char* __restrict__ kn) {
    const int lane = threadIdx.x & 63;
    const int wid  = threadIdx.x >> 6;
    const int base = blockIdx.x * 16 + wid * 4;
#pragma unroll
    for (int r = 0; r < 4; ++r) {
        const int row = base + r;                     // 0..32767
        const bool is_q = row < (B_ * N_);
        const int  rr   = is_q ? row : row - B_ * N_;
        const float* src = (is_q ? q : k) + (size_t)rr * C_;
        const float2 v = *(const float2*)(src + 2 * lane);
        const float ss = waveReduceSum(v.x * v.x + v.y * v.y);
        const float inv = 1.0f / fmaxf(sqrtf(ss), 1e-12f);
        if (is_q) {
            ushort2 o; o.x = f2bf(v.x * inv); o.y = f2bf(v.y * inv);
            *(ushort2*)(qn + (size_t)rr * C_ + 2 * lane) = o;   // 4 B/lane
        } else {
            const int pk = __builtin_amdgcn_cvt_pk_fp8_f32(v.x * inv, v.y * inv, 0, false);
            *(unsigned short*)(kn + (size_t)rr * C_ + 2 * lane) =
                (unsigned short)(pk & 0xffff);                  // 2 B/lane
        }
    }
}

// Kernel 2: one wave per q-row, 2 rows/wave. fp8 gather: a 128-elem k-row is
// 128 B = ONE cache line; 8 lanes cover it with a single uint4 load (16 fp8
// each). 9 passes: 0-7 = 64 negatives (one row per 8-lane group), pass 8 =
// positive row read by all lanes (coalesces to 1 line). Rows pre-normalized;
// decode via HW v_cvt_pk_f32_fp8. kn total = 2 MB; per-XCD hot slice with the
// batch swizzle = 512 KB -> fully L2-resident.
__global__ __launch_bounds__(256, 4) void infonce_kernel(
    const unsigned short* __restrict__ qn, const unsigned char* __restrict__ kn,
    const int* __restrict__ pos_idx, const int* __restrict__ neg_idx,
    float* __restrict__ partials) {
    __shared__ float wave_tot[4], wave_cnt[4];

    const int lane = threadIdx.x & 63;
    const int wid  = threadIdx.x >> 6;
    const int g    = lane >> 3;   // group 0..7
    const int s    = lane & 7;    // sub-lane within group

    const int batch = blockIdx.x & 15;   // XCD-affine batch mapping
    const int chunk = blockIdx.x >> 4;
    const int rbase = chunk * 8 + wid * 2;

    const unsigned char* kb = kn + (size_t)batch * (N_ * C_);

    float tot = 0.0f, cnt = 0.0f;

#pragma unroll
    for (int r = 0; r < 2; ++r) {
        const int n   = rbase + r;
        const int row = batch * N_ + n;

        // This lane's 16 q elements [s*16 .. s*16+15] from bf16 qn.
        const unsigned short* qrow = qn + (size_t)row * C_;
        float qf[16];
#pragma unroll
        for (int i = 0; i < 2; ++i) {
            const uint4 qu = *(const uint4*)(qrow + s * 16 + i * 8);
            qf[i*8+0] = bflo(qu.x); qf[i*8+1] = bfhi(qu.x);
            qf[i*8+2] = bflo(qu.y); qf[i*8+3] = bfhi(qu.y);
            qf[i*8+4] = bflo(qu.z); qf[i*8+5] = bfhi(qu.z);
            qf[i*8+6] = bflo(qu.w); qf[i*8+7] = bfhi(qu.w);
        }

        const int  pidx = pos_idx[row];     // wave-uniform
        const bool pval = pidx >= 0;
        const int  p0   = pval ? pidx : 0;

        const int my_nidx = neg_idx[(size_t)row * K_ + lane];  // coalesced
        int nidx[8];
#pragma unroll
        for (int p = 0; p < 8; ++p) nidx[p] = __shfl(my_nidx, p * 8 + g, 64);

        float d[9];
#pragma unroll
        for (int p = 0; p < 9; ++p) {
            const unsigned char* kr =
                (p < 8) ? kb + (size_t)(nidx[p] >= 0 ? nidx[p] : 0) * C_
                        : kb + (size_t)p0 * C_;
            const uint4 ku = *(const uint4*)(kr + s * 16);  // 16 fp8 elems
            float dot = 0.0f;
            const unsigned w[4] = {ku.x, ku.y, ku.z, ku.w};
#pragma unroll
            for (int i = 0; i < 4; ++i) {
                const f32x2 lo = __builtin_amdgcn_cvt_pk_f32_fp8(w[i], false);
                const f32x2 hi = __builtin_amdgcn_cvt_pk_f32_fp8(w[i], true);
                dot = fmaf(lo[0], qf[i*4+0], dot);
                dot = fmaf(lo[1], qf[i*4+1], dot);
                dot = fmaf(hi[0], qf[i*4+2], dot);
                dot = fmaf(hi[1], qf[i*4+3], dot);
            }
            dot += __shfl_xor(dot, 1, 64);   // intra-group-8: DPP-fast
            dot += __shfl_xor(dot, 2, 64);
            dot += __shfl_xor(dot, 4, 64);
            d[p] = dot;
        }

        // Pass 8 read identically by all groups -> d[8] wave-uniform.
        const float pos_sim = d[8] * INV_T;

        float simv[8];
#pragma unroll
        for (int p = 0; p < 8; ++p)
            simv[p] = (nidx[p] >= 0) ? d[p] * INV_T : -INFINITY;

        // logsumexp over [pos, 64 negs]; sims duplicated across each group's
        // 8 lanes -> only s==0 lanes contribute to the sum.
        float m = pos_sim;
#pragma unroll
        for (int p = 0; p < 8; ++p) m = fmaxf(m, simv[p]);
        m = waveReduceMax(m);
        float ssum = 0.0f;
        if (s == 0) {
#pragma unroll
            for (int p = 0; p < 8; ++p) ssum += __expf(simv[p] - m);
        }
        ssum = waveReduceSum(ssum) + __expf(pos_sim - m);
        const float per_patch = m + __logf(ssum) - pos_sim;

        if (pval) { tot += per_patch; cnt += 1.0f; }
    }

    if (lane == 0) { wave_tot[wid] = tot; wave_cnt[wid] = cnt; }
    __syncthreads();
    if (threadIdx.x == 0) {
        partials[2 * blockIdx.x]     = wave_tot[0] + wave_tot[1] + wave_tot[2] + wave_tot[3];
        partials[2 * blockIdx.x + 1] = wave_cnt[0] + wave_cnt[1] + wave_cnt[2] + wave_cnt[3];
    }
}

// Kernel 3: reduce block partials, emit total / count.
__global__ __launch_bounds__(256) void finalize_kernel(const float* __restrict__ partials,
                                                       float* __restrict__ out, int nblocks) {
    __shared__ float st[256], sc[256];
    float t = 0.0f, c = 0.0f;
    for (int i = threadIdx.x; i < nblocks; i += 256) {
        t += partials[2 * i];
        c += partials[2 * i + 1];
    }
    st[threadIdx.x] = t;
    sc[threadIdx.x] = c;
    __syncthreads();
    for (int off = 128; off > 0; off >>= 1) {
        if (threadIdx.x < off) {
            st[threadIdx.x] += st[threadIdx.x + off];
            sc[threadIdx.x] += sc[threadIdx.x + off];
        }
        __syncthreads();
    }
    if (threadIdx.x == 0) {
        const float cntv = sc[0];
        out[0] = (cntv > 0.0f) ? st[0] / fmaxf(cntv, 1.0f) : 0.0f;
    }
}

extern "C" void kernel_launch(void* const* d_in, const int* in_sizes, int n_in,
                              void* d_out, int out_size, void* d_ws, size_t ws_size,
                              hipStream_t stream) {
    const float* q   = (const float*)d_in[0];
    const float* k   = (const float*)d_in[1];
    const int*   pos = (const int*)d_in[2];
    const int*   neg = (const int*)d_in[3];
    float* out = (float*)d_out;

    float* wsf = (float*)d_ws;
    float* partials = wsf;                                   // 4096 floats
    unsigned short* qn = (unsigned short*)(wsf + 8192);      // 4 MB (bf16)
    unsigned char*  kn = (unsigned char*)(qn + (size_t)B_ * N_ * C_);  // 2 MB (fp8)

    normalize_kernel<<<2048, 256, 0, stream>>>(q, k, qn, kn);
    infonce_kernel<<<NBLK_MAIN, 256, 0, stream>>>(qn, kn, pos, neg, partials);
    finalize_kernel<<<1, 256, 0, stream>>>(partials, out, NBLK_MAIN);
}

// Round 6
// 86.156 us; speedup vs baseline: 1.1851x; 1.0193x over previous
//
#include <hip/hip_runtime.h>
#include <math.h>

#define B_ 16
#define N_ 1024
#define K_ 64
#define C_ 128
#define INV_T 14.285714285714286f  // 1/0.07
#define NBLK_MAIN 2048             // 8 rows per block (4 waves x 2 rows)

using f32x2 = __attribute__((ext_vector_type(2))) float;

__device__ __forceinline__ float waveReduceSum(float v) {
#pragma unroll
    for (int off = 32; off > 0; off >>= 1)
        v += __shfl_xor(v, off, 64);
    return v;
}

// fp32 -> bf16 round-to-nearest-even (finite normals only).
__device__ __forceinline__ unsigned short f2bf(float x) {
    unsigned u = __float_as_uint(x);
    return (unsigned short)((u + 0x7fffu + ((u >> 16) & 1u)) >> 16);
}
__device__ __forceinline__ float bflo(unsigned u) { return __uint_as_float(u << 16); }
__device__ __forceinline__ float bfhi(unsigned u) { return __uint_as_float(u & 0xffff0000u); }

// Kernel 1: L2-normalize. q rows -> bf16 qn PRE-SCALED by 1/T (4 MB);
// k rows -> fp8 e4m3 kn (2 MB, HW cvt). Wave per row, 4 rows/wave.
__global__ __launch_bounds__(256) void normalize_kernel(
    const float* __restrict__ q, const float* __restrict__ k,
    unsigned short* __restrict__ qn, unsigned char* __restrict__ kn) {
    const int lane = threadIdx.x & 63;
    const int wid  = threadIdx.x >> 6;
    const int base = blockIdx.x * 16 + wid * 4;
#pragma unroll
    for (int r = 0; r < 4; ++r) {
        const int row = base + r;                     // 0..32767
        const bool is_q = row < (B_ * N_);
        const int  rr   = is_q ? row : row - B_ * N_;
        const float* src = (is_q ? q : k) + (size_t)rr * C_;
        const float2 v = *(const float2*)(src + 2 * lane);
        const float ss = waveReduceSum(v.x * v.x + v.y * v.y);
        const float inv = 1.0f / fmaxf(sqrtf(ss), 1e-12f);
        if (is_q) {
            const float sc = inv * INV_T;             // fold 1/T into q
            ushort2 o; o.x = f2bf(v.x * sc); o.y = f2bf(v.y * sc);
            *(ushort2*)(qn + (size_t)rr * C_ + 2 * lane) = o;
        } else {
            const int pk = __builtin_amdgcn_cvt_pk_fp8_f32(v.x * inv, v.y * inv, 0, false);
            *(unsigned short*)(kn + (size_t)rr * C_ + 2 * lane) =
                (unsigned short)(pk & 0xffff);
        }
    }
}

// Kernel 2: one wave per q-row, 2 rows/wave. fp8 gather: one k-row = one
// 128B line; 8 lanes cover it with a single uint4 load. 9 passes: 0-7 = 64
// negatives (one row per 8-lane group), pass 8 = positive (all lanes, 1 line).
// Dot accumulates in f32x2 (v_pk_fma_f32); fp8 decode via HW cvt_pk_f32_fp8.
// Negative indices are loaded directly per-pass from the L1-hot 256B idx row
// (no ds_bpermute). LSE reductions use only the 3 cross-group xor levels
// {8,16,32} since sims are duplicated across each group's 8 lanes.
__global__ __launch_bounds__(256, 4) void infonce_kernel(
    const unsigned short* __restrict__ qn, const unsigned char* __restrict__ kn,
    const int* __restrict__ pos_idx, const int* __restrict__ neg_idx,
    float* __restrict__ partials) {
    __shared__ float wave_tot[4], wave_cnt[4];

    const int lane = threadIdx.x & 63;
    const int wid  = threadIdx.x >> 6;
    const int g    = lane >> 3;   // group 0..7
    const int s    = lane & 7;    // sub-lane within group

    const int batch = blockIdx.x & 15;   // XCD-affine batch mapping
    const int chunk = blockIdx.x >> 4;
    const int rbase = chunk * 8 + wid * 2;

    const unsigned char* kb = kn + (size_t)batch * (N_ * C_);

    float tot = 0.0f, cnt = 0.0f;

#pragma unroll
    for (int r = 0; r < 2; ++r) {
        const int n   = rbase + r;
        const int row = batch * N_ + n;

        // This lane's 16 q elements [s*16 .. s*16+15] as 8 f32x2 pairs.
        const unsigned short* qrow = qn + (size_t)row * C_;
        f32x2 qf[8];
#pragma unroll
        for (int i = 0; i < 2; ++i) {
            const uint4 qu = *(const uint4*)(qrow + s * 16 + i * 8);
            qf[i*4+0] = f32x2{bflo(qu.x), bfhi(qu.x)};
            qf[i*4+1] = f32x2{bflo(qu.y), bfhi(qu.y)};
            qf[i*4+2] = f32x2{bflo(qu.z), bfhi(qu.z)};
            qf[i*4+3] = f32x2{bflo(qu.w), bfhi(qu.w)};
        }

        const int  pidx = pos_idx[row];     // wave-uniform
        const bool pval = pidx >= 0;
        const int  p0   = pval ? pidx : 0;

        // Group g's 8 negative indices, loaded directly (256B row, L1-hot).
        const int* nrow = neg_idx + (size_t)row * K_;
        int nidx[8];
#pragma unroll
        for (int p = 0; p < 8; ++p) nidx[p] = nrow[p * 8 + g];

        float d[9];
#pragma unroll
        for (int p = 0; p < 9; ++p) {
            const unsigned char* kr =
                (p < 8) ? kb + (size_t)(nidx[p] >= 0 ? nidx[p] : 0) * C_
                        : kb + (size_t)p0 * C_;
            const uint4 ku = *(const uint4*)(kr + s * 16);  // 16 fp8 elems
            const unsigned w[4] = {ku.x, ku.y, ku.z, ku.w};
            f32x2 acc = f32x2{0.0f, 0.0f};
#pragma unroll
            for (int i = 0; i < 4; ++i) {
                const f32x2 lo = __builtin_amdgcn_cvt_pk_f32_fp8(w[i], false);
                const f32x2 hi = __builtin_amdgcn_cvt_pk_f32_fp8(w[i], true);
                acc = lo * qf[i*2+0] + acc;   // contracts to v_pk_fma_f32
                acc = hi * qf[i*2+1] + acc;
            }
            float dot = acc[0] + acc[1];
            dot += __shfl_xor(dot, 1, 64);   // intra-group: DPP-fast
            dot += __shfl_xor(dot, 2, 64);
            dot += __shfl_xor(dot, 4, 64);
            d[p] = dot;                       // == logit (q pre-scaled by 1/T)
        }

        const float pos_sim = d[8];           // wave-uniform

        float simv[8];
#pragma unroll
        for (int p = 0; p < 8; ++p)
            simv[p] = (nidx[p] >= 0) ? d[p] : -INFINITY;

        // Max: per-lane over its group's 8 sims, then 3 cross-group levels.
        float m = pos_sim;
#pragma unroll
        for (int p = 0; p < 8; ++p) m = fmaxf(m, simv[p]);
        m = fmaxf(m, __shfl_xor(m, 8, 64));
        m = fmaxf(m, __shfl_xor(m, 16, 64));
        m = fmaxf(m, __shfl_xor(m, 32, 64));

        // Sum: every lane sums its group's 8 exps (identical within group),
        // then 3 cross-group levels sum exactly one copy per group.
        float ssum = 0.0f;
#pragma unroll
        for (int p = 0; p < 8; ++p) ssum += __expf(simv[p] - m);
        ssum += __shfl_xor(ssum, 8, 64);
        ssum += __shfl_xor(ssum, 16, 64);
        ssum += __shfl_xor(ssum, 32, 64);
        ssum += __expf(pos_sim - m);

        const float per_patch = m + __logf(ssum) - pos_sim;
        if (pval) { tot += per_patch; cnt += 1.0f; }
    }

    if (lane == 0) { wave_tot[wid] = tot; wave_cnt[wid] = cnt; }
    __syncthreads();
    if (threadIdx.x == 0) {
        partials[2 * blockIdx.x]     = wave_tot[0] + wave_tot[1] + wave_tot[2] + wave_tot[3];
        partials[2 * blockIdx.x + 1] = wave_cnt[0] + wave_cnt[1] + wave_cnt[2] + wave_cnt[3];
    }
}

// Kernel 3: reduce block partials, emit total / count.
__global__ __launch_bounds__(256) void finalize_kernel(const float* __restrict__ partials,
                                                       float* __restrict__ out, int nblocks) {
    __shared__ float st[256], sc[256];
    float t = 0.0f, c = 0.0f;
    for (int i = threadIdx.x; i < nblocks; i += 256) {
        t += partials[2 * i];
        c += partials[2 * i + 1];
    }
    st[threadIdx.x] = t;
    sc[threadIdx.x] = c;
    __syncthreads();
    for (int off = 128; off > 0; off >>= 1) {
        if (threadIdx.x < off) {
            st[threadIdx.x] += st[threadIdx.x + off];
            sc[threadIdx.x] += sc[threadIdx.x + off];
        }
        __syncthreads();
    }
    if (threadIdx.x == 0) {
        const float cntv = sc[0];
        out[0] = (cntv > 0.0f) ? st[0] / fmaxf(cntv, 1.0f) : 0.0f;
    }
}

extern "C" void kernel_launch(void* const* d_in, const int* in_sizes, int n_in,
                              void* d_out, int out_size, void* d_ws, size_t ws_size,
                              hipStream_t stream) {
    const float* q   = (const float*)d_in[0];
    const float* k   = (const float*)d_in[1];
    const int*   pos = (const int*)d_in[2];
    const int*   neg = (const int*)d_in[3];
    float* out = (float*)d_out;

    float* wsf = (float*)d_ws;
    float* partials = wsf;                                   // 4096 floats
    unsigned short* qn = (unsigned short*)(wsf + 8192);      // 4 MB (bf16, pre-scaled)
    unsigned char*  kn = (unsigned char*)(qn + (size_t)B_ * N_ * C_);  // 2 MB (fp8)

    normalize_kernel<<<2048, 256, 0, stream>>>(q, k, qn, kn);
    infonce_kernel<<<NBLK_MAIN, 256, 0, stream>>>(qn, kn, pos, neg, partials);
    finalize_kernel<<<1, 256, 0, stream>>>(partials, out, NBLK_MAIN);
}